// Round 8
// baseline (431.408 us; speedup 1.0000x reference)
//
#include <hip/hip_runtime.h>

#define SEQ 512
#define TAGS 64
#define NB 128
#define START_TAG 62
#define STOP_TAG 63

// Single wave per batch. Lane j owns tag j. No barriers anywhere:
// p[] broadcast via LDS ping-pong with uniform-address ds_read_b128
// (intra-wave LDS ops are in-order; compiler inserts lgkmcnt waits).
__global__ __launch_bounds__(64) void crf_viterbi(const float* __restrict__ feats,
                                                  const void* __restrict__ maskp,
                                                  const float* __restrict__ trans,
                                                  int* __restrict__ out) {
    __shared__ __align__(16) float sA[TAGS];   // partition ping
    __shared__ __align__(16) float sB[TAGS];   // partition pong
    __shared__ unsigned char bp[SEQ * TAGS];   // backpointers, 32 KB

    const int b    = blockIdx.x;
    const int lane = threadIdx.x;              // 0..63 (one wave)

    // ---- sequence length from mask (dtype auto-detect; mask is a prefix of 1s) ----
    int lsum = 0;
    {
        const int* mi = (const int*)maskp;
        int w0 = mi[0];                          // first entry is always "true"
        if (w0 == 1) {                           // int32 0/1
            const int* row = mi + b * SEQ;
#pragma unroll
            for (int r = 0; r < 8; ++r) lsum += row[lane + 64 * r];
        } else if (w0 == 0x01010101) {           // bool bytes
            const int* row = (const int*)((const unsigned char*)maskp + b * SEQ);
#pragma unroll
            for (int r = 0; r < 2; ++r) {
                int v = row[lane + 64 * r];
                lsum += (v & 1) + ((v >> 8) & 1) + ((v >> 16) & 1) + ((v >> 24) & 1);
            }
        } else {                                 // float 1.0/0.0
            const float* row = (const float*)maskp + b * SEQ;
            float fa = 0.f;
#pragma unroll
            for (int r = 0; r < 8; ++r) fa += row[lane + 64 * r];
            lsum = (int)fa;
        }
#pragma unroll
        for (int off = 32; off >= 1; off >>= 1) lsum += __shfl_xor(lsum, off);
    }
    const int L = __builtin_amdgcn_readfirstlane(lsum);

    // ---- full transition column set in registers: tw[i] = trans[i][lane] ----
    float tw[TAGS];
#pragma unroll
    for (int i = 0; i < TAGS; ++i) tw[i] = trans[i * TAGS + lane];
    const float tstop  = trans[lane * TAGS + STOP_TAG];   // trans[j][STOP]
    const float tstart = trans[START_TAG * TAGS + lane];  // trans[START][j]

    const float* frow = feats + (size_t)b * SEQ * TAGS;
    float pv = frow[lane] + tstart;              // partition t=0; lane j holds p[j]
    sA[lane] = pv;

    // 2-deep feats prefetch (rows 1,2 always exist: L >= 128)
    float fcur  = frow[TAGS + lane];
    float fnext = frow[2 * TAGS + lane];

    int t = 1;
    // One forward step: read p (broadcast b128) from src, compute argmax over all
    // 64 prev-tags in-register (grouped tournament, first-occurrence ties), write
    // new partition to dst. Exact reference association: (fcur + tw[i]) + p[i].
    auto STEP = [&](const float* __restrict__ src, float* __restrict__ dst) {
        float gv[8]; int gi[8];
#pragma unroll
        for (int g = 0; g < 8; ++g) {
            float4 pA = *(const float4*)&src[g * 8];      // uniform addr -> broadcast
            float4 pB = *(const float4*)&src[g * 8 + 4];
            float pk[8] = {pA.x, pA.y, pA.z, pA.w, pB.x, pB.y, pB.z, pB.w};
            float v[8]; int id[8];
#pragma unroll
            for (int k = 0; k < 8; ++k) {
                v[k]  = (fcur + tw[g * 8 + k]) + pk[k];
                id[k] = g * 8 + k;
            }
#pragma unroll
            for (int s = 1; s < 8; s <<= 1) {
#pragma unroll
                for (int k = 0; k < 8; k += 2 * s) {
                    bool c = v[k + s] > v[k];             // left wins ties
                    v[k]  = c ? v[k + s]  : v[k];
                    id[k] = c ? id[k + s] : id[k];
                }
            }
            gv[g] = v[0]; gi[g] = id[0];
        }
#pragma unroll
        for (int s = 1; s < 8; s <<= 1) {
#pragma unroll
            for (int g = 0; g < 8; g += 2 * s) {
                bool c = gv[g + s] > gv[g];
                gv[g] = c ? gv[g + s] : gv[g];
                gi[g] = c ? gi[g + s] : gi[g];
            }
        }
        bp[t * TAGS + lane] = (unsigned char)gi[0];
        pv = gv[0];
        dst[lane] = pv;
        // rotate feats prefetch (2 rows ahead)
        fcur = fnext;
        int tn = t + 2; tn = tn < SEQ ? tn : SEQ - 1;
        fnext = frow[tn * TAGS + lane];
        ++t;
    };

    while (t < L) {
        STEP(sA, sB);
        if (t >= L) break;
        STEP(sB, sA);
    }

    // ---- pointer0 = argmax_i( p[i] + trans[i][STOP] ), first-occurrence ties ----
    float v = pv + tstop; int idx = lane;
#pragma unroll
    for (int off = 32; off >= 1; off >>= 1) {
        float ov = __shfl_xor(v, off);
        int   oi = __shfl_xor(idx, off);
        bool take = (ov > v) || (ov == v && oi < idx);
        v   = take ? ov : v;
        idx = take ? oi : idx;
    }
    const int ptr0 = __builtin_amdgcn_readfirstlane(idx);

    int* outrow = out + b * SEQ;
    // tail: decode[L-1] = ptr0, decode[S-1] = ptr0, (L-1, S-1) exclusive = 0
    for (int s = lane; s < SEQ; s += 64) {
        if (s == L - 1 || s == SEQ - 1) outrow[s] = ptr0;
        else if (s > L - 1)             outrow[s] = 0;
    }

    // ---- backtrace (same wave wrote bp; in-order LDS, no sync needed) ----
    {
        int ptr = ptr0;
        int tt = L - 2;
        while (tt >= 7) {
            // prefetch 8 bp rows into lanes (independent of the chase)
            int r0 = bp[(tt + 1) * TAGS + lane];
            int r1 = bp[(tt    ) * TAGS + lane];
            int r2 = bp[(tt - 1) * TAGS + lane];
            int r3 = bp[(tt - 2) * TAGS + lane];
            int r4 = bp[(tt - 3) * TAGS + lane];
            int r5 = bp[(tt - 4) * TAGS + lane];
            int r6 = bp[(tt - 5) * TAGS + lane];
            int r7 = bp[(tt - 6) * TAGS + lane];
            // dependent chain is cheap v_readlane with uniform (SGPR) index
            ptr = __builtin_amdgcn_readlane(r0, ptr); if (lane == 0) outrow[tt    ] = ptr;
            ptr = __builtin_amdgcn_readlane(r1, ptr); if (lane == 0) outrow[tt - 1] = ptr;
            ptr = __builtin_amdgcn_readlane(r2, ptr); if (lane == 0) outrow[tt - 2] = ptr;
            ptr = __builtin_amdgcn_readlane(r3, ptr); if (lane == 0) outrow[tt - 3] = ptr;
            ptr = __builtin_amdgcn_readlane(r4, ptr); if (lane == 0) outrow[tt - 4] = ptr;
            ptr = __builtin_amdgcn_readlane(r5, ptr); if (lane == 0) outrow[tt - 5] = ptr;
            ptr = __builtin_amdgcn_readlane(r6, ptr); if (lane == 0) outrow[tt - 6] = ptr;
            ptr = __builtin_amdgcn_readlane(r7, ptr); if (lane == 0) outrow[tt - 7] = ptr;
            tt -= 8;
        }
        while (tt >= 0) {
            ptr = bp[(tt + 1) * TAGS + ptr];     // uniform-address LDS broadcast
            if (lane == 0) outrow[tt] = ptr;
            tt--;
        }
    }
}

extern "C" void kernel_launch(void* const* d_in, const int* in_sizes, int n_in,
                              void* d_out, int out_size, void* d_ws, size_t ws_size,
                              hipStream_t stream) {
    const float* feats = (const float*)d_in[0];
    const void*  maskp = d_in[1];
    // d_in[2] = tags (unused by the reference decode)
    const float* trans = (const float*)d_in[3];
    int* out = (int*)d_out;
    crf_viterbi<<<NB, 64, 0, stream>>>(feats, maskp, trans, out);
}